// Round 12
// baseline (1042.224 us; speedup 1.0000x reference)
//
#include <hip/hip_runtime.h>
#include <hip/hip_bf16.h>
#include <stdint.h>

// Problem dims
#define BATCH 256
#define SEQ   512
#define INDIM 64
#define H     128
#define RB    4                 // batch rows per tile
#define CH    16                // h0 handoff chunk (steps)
#define NCH   (SEQ / CH)        // 32 chunks
#define NBLK  32                // producer (and consumer) block count; 2 tiles/block

// workspace layout (bytes)
#define WS_XB     0u            // bf16[256*512*64]                   16,777,216
#define WS_H0RING 16777216u     // bf16[64 tiles][4 slots][64][128]    4,194,304
#define WS_WB     20971520u     // bf16 weights 229376 elems             458,752
#define WS_BSUM   21430272u     // f32[1024]                               4,096
#define WS_FLAGS  21434368u     // int[128]                                  512
// wb element offsets
#define WB_IH0 0
#define WB_HH0 32768
#define WB_IH1 98304
#define WB_HH1 163840
#define WB_TOT 229376

using short8  = __attribute__((ext_vector_type(8))) short;
using float4v = __attribute__((ext_vector_type(4))) float;

#define LOG2E 1.4426950408889634f

__device__ __forceinline__ unsigned short f2bf(float f) {
    union { float f; uint32_t u; } v; v.f = f;
    uint32_t u = v.u;
    return (unsigned short)((u + 0x7FFFu + ((u >> 16) & 1u)) >> 16); // RNE
}
__device__ __forceinline__ float fast_exp2(float x) {
#if __has_builtin(__builtin_amdgcn_exp2f)
    return __builtin_amdgcn_exp2f(x);
#else
    return __expf(x * 0.6931471805599453f);
#endif
}
__device__ __forceinline__ float fast_rcp(float x) {
#if __has_builtin(__builtin_amdgcn_rcpf)
    return __builtin_amdgcn_rcpf(x);
#else
    return 1.f / x;
#endif
}
__device__ __forceinline__ float sigmoid_fast(float x) {
    return fast_rcp(1.f + fast_exp2(-LOG2E * x));
}
__device__ __forceinline__ float tanh_fast(float x) {
    return fmaf(-2.f, fast_rcp(1.f + fast_exp2((2.f * LOG2E) * x)), 1.f);
}
__device__ __forceinline__ void light_barrier() {
    asm volatile("s_waitcnt lgkmcnt(0)\n\ts_barrier" ::: "memory");
}
__device__ __forceinline__ void spin_ge(const int* f, int target) {
    while (__hip_atomic_load(f, __ATOMIC_RELAXED, __HIP_MEMORY_SCOPE_AGENT) < target)
        __builtin_amdgcn_s_sleep(2);
    (void)__hip_atomic_load(f, __ATOMIC_ACQUIRE, __HIP_MEMORY_SCOPE_AGENT);
}
__device__ __forceinline__ void bump(int* f) {
    __hip_atomic_fetch_add(f, 1, __ATOMIC_RELEASE, __HIP_MEMORY_SCOPE_AGENT);
}

// Single shared-memory footprint for ALL role/template variants.
// R11 FAILURE: function-scope __shared__ inside the templated device function
// was duplicated per inlined instantiation (2 x 85 KB = 171 KB > 160 KB).
// Declaring it ONCE in the kernel and passing a pointer shares the allocation.
struct Smem {
    float gbuf[2][2][2][512][4];   // [tile][sb][io][rec-tid][gate] — 64 KB
    short hbuf[2][2][16][132];     // [tile][cur][row][col] — pad 132 (2-way free)
    float hl[8][128];
    float mid[8][65];
};                                  // 88,608 B total

// ---------------- prep 1: x fp32 -> bf16 ----------------
__global__ void conv_x_kernel(const float* __restrict__ x, unsigned short* __restrict__ xb) {
    int i = blockIdx.x * blockDim.x + threadIdx.x;
    float4 f = ((const float4*)x)[i];
    ushort4 o;
    o.x = f2bf(f.x); o.y = f2bf(f.y); o.z = f2bf(f.z); o.w = f2bf(f.w);
    ((ushort4*)xb)[i] = o;
}

// ---------------- prep 2: weights->bf16, bias sums, flag zero ----------------
__global__ void prep_w_kernel(const float* __restrict__ Wih0, const float* __restrict__ Whh0,
                              const float* __restrict__ Wih1, const float* __restrict__ Whh1,
                              const float* __restrict__ bih0, const float* __restrict__ bhh0,
                              const float* __restrict__ bih1, const float* __restrict__ bhh1,
                              unsigned short* __restrict__ wb, float* __restrict__ bsum,
                              int* __restrict__ flags) {
    int gid = blockIdx.x * blockDim.x + threadIdx.x;   // grid = 896*256 = WB_TOT
    float v;
    if      (gid < WB_HH0) v = Wih0[gid];
    else if (gid < WB_IH1) v = Whh0[gid - WB_HH0];
    else if (gid < WB_HH1) v = Wih1[gid - WB_IH1];
    else                   v = Whh1[gid - WB_HH1];
    wb[gid] = f2bf(v);
    if (gid < 512)       bsum[gid] = bih0[gid] + bhh0[gid];
    else if (gid < 1024) bsum[gid] = bih1[gid - 512] + bhh1[gid - 512];
    if (gid < 128) flags[gid] = 0;
}

// ---------------- fused block: 2 interleaved batch tiles ----------------
// 64 blocks x 1024 threads. Blocks 0..31 = layer0 (producer) on tiles {2b,2b+1};
// 32..63 = layer1 (consumer) on same tiles. Waves 0..7 = recurrence (whh only),
// waves 8..15 = gate-init helpers (wih shared). ONE barrier round advances BOTH
// tiles one timestep: tile A's activation chain overlaps tile B's MFMA chain,
// amortizing the fixed per-round cost (barrier + LDS turnaround + trans chain)
// that pinned R4/R7/R10 at ~2100 cyc/step across three structures.
template<int KIN, bool IS_PROD>
__device__ __forceinline__ void lstm_block(
    Smem* sm,
    const unsigned short* __restrict__ xb,    // producer A source (x, global layout)
    unsigned short* __restrict__ hrA,         // h0 ring tile A
    unsigned short* __restrict__ hrB,
    const unsigned short* __restrict__ w_ih,  // bf16 [512][KIN]
    const unsigned short* __restrict__ w_hh,  // bf16 [512][128]
    const float* __restrict__ bsum,           // [512]
    const float* __restrict__ W1, const float* __restrict__ b1,
    const float* __restrict__ W2, const float* __restrict__ b2,
    float* __restrict__ out,
    int* __restrict__ prodprog, int* __restrict__ consprog, int btA)
{
    constexpr int KT = KIN / 32;
    const int tid  = threadIdx.x;
    const int wave = tid >> 6, lane = tid & 63, quad = lane >> 4, l16 = lane & 15;

    if (wave < 8) {
        // ================= RECURRENCE WAVES =================
        const int cell = wave * 16 + l16;
        const int arow = l16 & 12;
        for (int i = tid; i < 2 * 2 * 16 * 132; i += 512) ((short*)sm->hbuf)[i] = 0;

        short8 whh_f[4][4];                   // shared by both tiles (same layer)
#pragma unroll
        for (int tT = 0; tT < 4; tT++)
#pragma unroll
            for (int kt = 0; kt < 4; kt++)
                whh_f[tT][kt] = *(const short8*)(w_hh + (size_t)(tT * 128 + cell) * H + kt * 32 + quad * 8);

        if (!IS_PROD && tid == 0) spin_ge(prodprog, 2);
        __syncthreads();   // B1
        __syncthreads();   // B2: helper prologue done (window 0 in gbuf[.][0])
        float cA = 0.f, cB = 0.f;

        auto rstep = [&](int CUR, int SB, unsigned short* hsA, unsigned short* hsB,
                         int i, bool last) __attribute__((always_inline)) {
            // ---- tile A: gates
            short8 h0 = *(const short8*)&sm->hbuf[0][CUR][arow][0 * 32 + quad * 8];
            short8 h1 = *(const short8*)&sm->hbuf[0][CUR][arow][1 * 32 + quad * 8];
            short8 h2 = *(const short8*)&sm->hbuf[0][CUR][arow][2 * 32 + quad * 8];
            short8 h3 = *(const short8*)&sm->hbuf[0][CUR][arow][3 * 32 + quad * 8];
            float4 giA = *(const float4*)&sm->gbuf[0][SB][CUR][tid][0];
            float4v a0 = (float4v){giA.x, 0.f, 0.f, 0.f};
            float4v a1 = (float4v){giA.y, 0.f, 0.f, 0.f};
            float4v a2 = (float4v){giA.z, 0.f, 0.f, 0.f};
            float4v a3 = (float4v){giA.w, 0.f, 0.f, 0.f};
            a0 = __builtin_amdgcn_mfma_f32_16x16x32_bf16(h0, whh_f[0][0], a0, 0, 0, 0);
            a1 = __builtin_amdgcn_mfma_f32_16x16x32_bf16(h0, whh_f[1][0], a1, 0, 0, 0);
            a2 = __builtin_amdgcn_mfma_f32_16x16x32_bf16(h0, whh_f[2][0], a2, 0, 0, 0);
            a3 = __builtin_amdgcn_mfma_f32_16x16x32_bf16(h0, whh_f[3][0], a3, 0, 0, 0);
            a0 = __builtin_amdgcn_mfma_f32_16x16x32_bf16(h1, whh_f[0][1], a0, 0, 0, 0);
            a1 = __builtin_amdgcn_mfma_f32_16x16x32_bf16(h1, whh_f[1][1], a1, 0, 0, 0);
            a2 = __builtin_amdgcn_mfma_f32_16x16x32_bf16(h1, whh_f[2][1], a2, 0, 0, 0);
            a3 = __builtin_amdgcn_mfma_f32_16x16x32_bf16(h1, whh_f[3][1], a3, 0, 0, 0);
            a0 = __builtin_amdgcn_mfma_f32_16x16x32_bf16(h2, whh_f[0][2], a0, 0, 0, 0);
            a1 = __builtin_amdgcn_mfma_f32_16x16x32_bf16(h2, whh_f[1][2], a1, 0, 0, 0);
            a2 = __builtin_amdgcn_mfma_f32_16x16x32_bf16(h2, whh_f[2][2], a2, 0, 0, 0);
            a3 = __builtin_amdgcn_mfma_f32_16x16x32_bf16(h2, whh_f[3][2], a3, 0, 0, 0);
            a0 = __builtin_amdgcn_mfma_f32_16x16x32_bf16(h3, whh_f[0][3], a0, 0, 0, 0);
            a1 = __builtin_amdgcn_mfma_f32_16x16x32_bf16(h3, whh_f[1][3], a1, 0, 0, 0);
            a2 = __builtin_amdgcn_mfma_f32_16x16x32_bf16(h3, whh_f[2][3], a2, 0, 0, 0);
            a3 = __builtin_amdgcn_mfma_f32_16x16x32_bf16(h3, whh_f[3][3], a3, 0, 0, 0);
            float gA0 = a0[0], gA1 = a1[0], gA2 = a2[0], gA3 = a3[0];
            // ---- tile B: gates
            short8 k0 = *(const short8*)&sm->hbuf[1][CUR][arow][0 * 32 + quad * 8];
            short8 k1 = *(const short8*)&sm->hbuf[1][CUR][arow][1 * 32 + quad * 8];
            short8 k2 = *(const short8*)&sm->hbuf[1][CUR][arow][2 * 32 + quad * 8];
            short8 k3 = *(const short8*)&sm->hbuf[1][CUR][arow][3 * 32 + quad * 8];
            float4 giB = *(const float4*)&sm->gbuf[1][SB][CUR][tid][0];
            float4v c0v = (float4v){giB.x, 0.f, 0.f, 0.f};
            float4v c1v = (float4v){giB.y, 0.f, 0.f, 0.f};
            float4v c2v = (float4v){giB.z, 0.f, 0.f, 0.f};
            float4v c3v = (float4v){giB.w, 0.f, 0.f, 0.f};
            c0v = __builtin_amdgcn_mfma_f32_16x16x32_bf16(k0, whh_f[0][0], c0v, 0, 0, 0);
            c1v = __builtin_amdgcn_mfma_f32_16x16x32_bf16(k0, whh_f[1][0], c1v, 0, 0, 0);
            c2v = __builtin_amdgcn_mfma_f32_16x16x32_bf16(k0, whh_f[2][0], c2v, 0, 0, 0);
            c3v = __builtin_amdgcn_mfma_f32_16x16x32_bf16(k0, whh_f[3][0], c3v, 0, 0, 0);
            c0v = __builtin_amdgcn_mfma_f32_16x16x32_bf16(k1, whh_f[0][1], c0v, 0, 0, 0);
            c1v = __builtin_amdgcn_mfma_f32_16x16x32_bf16(k1, whh_f[1][1], c1v, 0, 0, 0);
            c2v = __builtin_amdgcn_mfma_f32_16x16x32_bf16(k1, whh_f[2][1], c2v, 0, 0, 0);
            c3v = __builtin_amdgcn_mfma_f32_16x16x32_bf16(k1, whh_f[3][1], c3v, 0, 0, 0);
            c0v = __builtin_amdgcn_mfma_f32_16x16x32_bf16(k2, whh_f[0][2], c0v, 0, 0, 0);
            c1v = __builtin_amdgcn_mfma_f32_16x16x32_bf16(k2, whh_f[1][2], c1v, 0, 0, 0);
            c2v = __builtin_amdgcn_mfma_f32_16x16x32_bf16(k2, whh_f[2][2], c2v, 0, 0, 0);
            c3v = __builtin_amdgcn_mfma_f32_16x16x32_bf16(k2, whh_f[3][2], c3v, 0, 0, 0);
            c0v = __builtin_amdgcn_mfma_f32_16x16x32_bf16(k3, whh_f[0][3], c0v, 0, 0, 0);
            c1v = __builtin_amdgcn_mfma_f32_16x16x32_bf16(k3, whh_f[1][3], c1v, 0, 0, 0);
            c2v = __builtin_amdgcn_mfma_f32_16x16x32_bf16(k3, whh_f[2][3], c2v, 0, 0, 0);
            c3v = __builtin_amdgcn_mfma_f32_16x16x32_bf16(k3, whh_f[3][3], c3v, 0, 0, 0);
            float gB0 = c0v[0], gB1 = c1v[0], gB2 = c2v[0], gB3 = c3v[0];
            // ---- activation A (overlaps B's MFMA tail via scheduler)
            {
                float si = sigmoid_fast(gA0), sf = sigmoid_fast(gA1);
                float tg = tanh_fast(gA2),   so = sigmoid_fast(gA3);
                float cn = fmaf(sf, cA, si * tg);
                cA = cn;
                float h = so * tanh_fast(cn);
                const unsigned short hbv = f2bf(h);
                sm->hbuf[0][CUR ^ 1][quad * 4][cell] = (short)hbv;
                if (IS_PROD) hsA[(size_t)(i * 4 + quad) * H + cell] = hbv;
                else if (last) sm->hl[quad][cell] = h;
            }
            // ---- activation B
            {
                float si = sigmoid_fast(gB0), sf = sigmoid_fast(gB1);
                float tg = tanh_fast(gB2),   so = sigmoid_fast(gB3);
                float cn = fmaf(sf, cB, si * tg);
                cB = cn;
                float h = so * tanh_fast(cn);
                const unsigned short hbv = f2bf(h);
                sm->hbuf[1][CUR ^ 1][quad * 4][cell] = (short)hbv;
                if (IS_PROD) hsB[(size_t)(i * 4 + quad) * H + cell] = hbv;
                else if (last) sm->hl[4 + quad][cell] = h;
            }
            light_barrier();
        };

        for (int ch = 0; ch < NCH; ch++) {
            unsigned short* hsA = IS_PROD ? hrA + (size_t)(ch & 3) * (64 * H) : nullptr;
            unsigned short* hsB = IS_PROD ? hrB + (size_t)(ch & 3) * (64 * H) : nullptr;
            const bool lastCh = (ch == NCH - 1);
#pragma unroll 1
            for (int i = 0; i < CH; i += 4) {
                rstep(0, 0, hsA, hsB, i + 0, false);
                rstep(1, 0, hsA, hsB, i + 1, false);
                rstep(0, 1, hsA, hsB, i + 2, false);
                rstep(1, 1, hsA, hsB, i + 3, lastCh && (i + 3 == CH - 1));
            }
            __syncthreads();   // B3: drains producer's global h stores
            if (tid == 0) {
                bump(IS_PROD ? prodprog : consprog);
                if (ch + 1 < NCH) {
                    if (IS_PROD) { if (ch + 1 >= 4) spin_ge(consprog, ch - 2); }
                    else { int t = ch + 3 < NCH ? ch + 3 : NCH; spin_ge(prodprog, t); }
                }
            }
            __syncthreads();   // B4
        }
    } else {
        // ================= HELPER WAVES =================
        const int hw = wave - 8;
        const int b0A = btA * RB, b0B = b0A + RB;
        short8 wih_f[4][KT];                  // shared across both tiles
        float  bias4[4];
#pragma unroll
        for (int j = 0; j < 4; j++) {
            const int n = hw * 64 + j * 16 + l16;
#pragma unroll
            for (int kt = 0; kt < KT; kt++)
                wih_f[j][kt] = *(const short8*)(w_ih + (size_t)n * KIN + kt * 32 + quad * 8);
            bias4[j] = bsum[n];
        }
        const int m = l16 & 7, ro = m & 3, dio = m >> 2;

        auto loadAfrag = [&](short8 (&af)[KT], const unsigned short* ring, int b0r, int tw0)
            __attribute__((always_inline)) {
            const int t_tok = tw0 + dio;
            const unsigned short* ap;
            if (IS_PROD)
                ap = xb + ((size_t)(b0r + ro) * SEQ + t_tok) * KIN + quad * 8;
            else
                ap = ring + (size_t)((t_tok >> 4) & 3) * (64 * H)
                          + (size_t)((t_tok & 15) * 4 + ro) * H + quad * 8;
#pragma unroll
            for (int kt = 0; kt < KT; kt++) af[kt] = *(const short8*)(ap + kt * 32);
        };
        auto compWin = [&](short8 (&af)[KT], int TILE, int SBD) __attribute__((always_inline)) {
#pragma unroll
            for (int j = 0; j < 4; j++) {
                const int cg = (hw * 4 + j) & 7, tT = (hw * 4 + j) >> 3;
                const float bs = bias4[j];
                float4v acc = (float4v){bs, bs, bs, bs};
#pragma unroll
                for (int kt = 0; kt < KT; kt++)
                    acc = __builtin_amdgcn_mfma_f32_16x16x32_bf16(af[kt], wih_f[j][kt], acc, 0, 0, 0);
                if (quad < 2) {                 // io = quad (2-step window)
#pragma unroll
                    for (int reg = 0; reg < 4; reg++)
                        sm->gbuf[TILE][SBD][quad][cg * 64 + reg * 16 + l16][tT] = acc[reg];
                }
            }
        };

        short8 afA[KT], afB[KT];
        __syncthreads();   // B1 (after rec's consumer spin — h0 chunks 0,1 ready)
        // prologue: window 0 -> gbuf[.][0]; preload window 1
        loadAfrag(afA, hrA, b0A, 0); compWin(afA, 0, 0);
        loadAfrag(afB, hrB, b0B, 0); compWin(afB, 1, 0);
        loadAfrag(afA, hrA, b0A, 2);
        loadAfrag(afB, hrB, b0B, 2);
        __syncthreads();   // B2

        for (int ch = 0; ch < NCH; ch++) {
            const int r0 = ch * CH;
#pragma unroll 1
            for (int i = 0; i < CH; i += 4) {
                const int r = r0 + i;
                // round r (even): tile A of window r/2+1 -> SBD 1; reload afA
                if (r + 2 < SEQ) compWin(afA, 0, 1);
                if (r + 4 < SEQ) loadAfrag(afA, hrA, b0A, r + 4);
                light_barrier();
                // round r+1 (odd): tile B of window r/2+1
                if (r + 3 < SEQ) compWin(afB, 1, 1);
                if (r + 5 < SEQ) loadAfrag(afB, hrB, b0B, r + 4);
                light_barrier();
                // round r+2: tile A of window r/2+2 -> SBD 0
                if (r + 4 < SEQ) compWin(afA, 0, 0);
                if (r + 6 < SEQ) loadAfrag(afA, hrA, b0A, r + 6);
                light_barrier();
                // round r+3: tile B of window r/2+2
                if (r + 5 < SEQ) compWin(afB, 1, 0);
                if (r + 7 < SEQ) loadAfrag(afB, hrB, b0B, r + 6);
                light_barrier();
            }
            __syncthreads();   // B3
            __syncthreads();   // B4
        }
    }

    if (!IS_PROD) {
        // ---- MLP head for this block's 8 rows (2 tiles) ----
        if (tid < 512) {
            const int row = tid >> 6, j = tid & 63;
            float s = b1[j];
            const float* wr = W1 + (size_t)j * 128;
#pragma unroll 8
            for (int k = 0; k < 128; k++) s = fmaf(sm->hl[row][k], wr[k], s);
            sm->mid[row][j] = fmaxf(s, 0.f);
        }
        __syncthreads();
        if (tid < 24) {
            const int row = tid / 3, k = tid - row * 3;
            float o = b2[k];
            const float* wr = W2 + (size_t)k * 64;
#pragma unroll 8
            for (int j = 0; j < 64; j++) o = fmaf(sm->mid[row][j], wr[j], o);
            out[(size_t)(btA * RB + row) * 3 + k] = o;
        }
    }
}

__global__ __launch_bounds__(1024)
void lstm_fused_kernel(const unsigned short* __restrict__ xb,
                       const unsigned short* __restrict__ wb,
                       const float* __restrict__ bsum,
                       unsigned short* __restrict__ h0ring,
                       const float* __restrict__ W1, const float* __restrict__ b1,
                       const float* __restrict__ W2, const float* __restrict__ b2,
                       float* __restrict__ out, int* __restrict__ flags)
{
    __shared__ Smem sm;                 // ONE copy shared by both role branches
    int* prodprog = flags;
    int* consprog = flags + NBLK;
    if (blockIdx.x < NBLK) {
        const int bid = blockIdx.x;
        lstm_block<64, true>(&sm, xb,
                             h0ring + (size_t)(2 * bid) * (4 * 64 * H),
                             h0ring + (size_t)(2 * bid + 1) * (4 * 64 * H),
                             wb + WB_IH0, wb + WB_HH0, bsum,
                             W1, b1, W2, b2, out,
                             &prodprog[bid], &consprog[bid], 2 * bid);
    } else {
        const int bid = blockIdx.x - NBLK;
        lstm_block<128, false>(&sm, xb,
                               h0ring + (size_t)(2 * bid) * (4 * 64 * H),
                               h0ring + (size_t)(2 * bid + 1) * (4 * 64 * H),
                               wb + WB_IH1, wb + WB_HH1, bsum + 512,
                               W1, b1, W2, b2, out,
                               &prodprog[bid], &consprog[bid], 2 * bid);
    }
}

extern "C" void kernel_launch(void* const* d_in, const int* in_sizes, int n_in,
                              void* d_out, int out_size, void* d_ws, size_t ws_size,
                              hipStream_t stream) {
    const float* x     = (const float*)d_in[0];
    const float* W_ih0 = (const float*)d_in[1];
    const float* W_hh0 = (const float*)d_in[2];
    const float* b_ih0 = (const float*)d_in[3];
    const float* b_hh0 = (const float*)d_in[4];
    const float* W_ih1 = (const float*)d_in[5];
    const float* W_hh1 = (const float*)d_in[6];
    const float* b_ih1 = (const float*)d_in[7];
    const float* b_hh1 = (const float*)d_in[8];
    const float* W1    = (const float*)d_in[9];
    const float* b1    = (const float*)d_in[10];
    const float* W2    = (const float*)d_in[11];
    const float* b2    = (const float*)d_in[12];
    float* out = (float*)d_out;

    char* ws = (char*)d_ws;
    unsigned short* xb    = (unsigned short*)(ws + WS_XB);
    unsigned short* h0r   = (unsigned short*)(ws + WS_H0RING);
    unsigned short* wb    = (unsigned short*)(ws + WS_WB);
    float*          bsum  = (float*)(ws + WS_BSUM);
    int*            flags = (int*)(ws + WS_FLAGS);

    conv_x_kernel<<<8192, 256, 0, stream>>>(x, xb);
    prep_w_kernel<<<896, 256, 0, stream>>>(W_ih0, W_hh0, W_ih1, W_hh1,
                                           b_ih0, b_hh0, b_ih1, b_hh1, wb, bsum, flags);
    lstm_fused_kernel<<<2 * NBLK, 1024, 0, stream>>>(xb, wb, bsum, h0r,
                                                     W1, b1, W2, b2, out, flags);
}